// Round 3
// baseline (749.580 us; speedup 1.0000x reference)
//
#include <hip/hip_runtime.h>
#include <stdint.h>

#define BATCH 32
#define BC    8            // batch chunk
#define CCH   512
#define NPIX  1024
#define HEADS 8

typedef short bf16x8 __attribute__((ext_vector_type(8)));
typedef float f32x4 __attribute__((ext_vector_type(4)));

__device__ inline float bf2f(unsigned short u) {
  union { float f; uint32_t i; } t; t.i = ((uint32_t)u) << 16; return t.f;
}
__device__ inline unsigned short f2bf(float f) {
  union { float f; uint32_t u; } t; t.f = f;
  uint32_t u = t.u;
  return (unsigned short)((u + 0x7FFFu + ((u >> 16) & 1u)) >> 16);
}

// ---------------- transpose fp32 [b,R,Cc] -> bf16 [b,Cc,R] -------------------
__global__ void transpose_f2b(const float* __restrict__ in,
                              unsigned short* __restrict__ out, int R, int Cc) {
  __shared__ float tile[32][33];
  int b = blockIdx.z;
  int c0 = blockIdx.x * 32;
  int r0 = blockIdx.y * 32;
  const float* inb = in + (size_t)b * R * Cc;
  unsigned short* outb = out + (size_t)b * R * Cc;
  int tx = threadIdx.x, ty = threadIdx.y;
  for (int i = 0; i < 4; i++) {
    int r = ty + i * 8;
    tile[r][tx] = inb[(size_t)(r0 + r) * Cc + c0 + tx];
  }
  __syncthreads();
  for (int i = 0; i < 4; i++) {
    int r = ty + i * 8;
    outb[(size_t)(c0 + r) * R + r0 + tx] = f2bf(tile[tx][r]);
  }
}

// ---------------- transpose bf16 [b,R,Cc] -> bf16 [b,Cc,R] -------------------
__global__ void transpose_b2b(const unsigned short* __restrict__ in,
                              unsigned short* __restrict__ out, int R, int Cc) {
  __shared__ unsigned short tile[32][33];
  int b = blockIdx.z;
  int c0 = blockIdx.x * 32;
  int r0 = blockIdx.y * 32;
  const unsigned short* inb = in + (size_t)b * R * Cc;
  unsigned short* outb = out + (size_t)b * R * Cc;
  int tx = threadIdx.x, ty = threadIdx.y;
  for (int i = 0; i < 4; i++) {
    int r = ty + i * 8;
    tile[r][tx] = inb[(size_t)(r0 + r) * Cc + c0 + tx];
  }
  __syncthreads();
  for (int i = 0; i < 4; i++) {
    int r = ty + i * 8;
    outb[(size_t)(c0 + r) * R + r0 + tx] = tile[tx][r];
  }
}

// ---------------- gemm_bt: C[b][m][n] = sum_k A[m][k]*X[b][n][k] -------------
// A [M,K] fp32 (converted to bf16 during staging); X [b,N,K] bf16.
// OUT_F32: write float output (+bias), else bf16 (no bias).
#define APITCH 40
template <bool OUT_F32>
__launch_bounds__(256)
__global__ void gemm_bt(const float* __restrict__ A,
                        const unsigned short* __restrict__ X,
                        void* __restrict__ Cout,
                        const float* __restrict__ bias,
                        int M, int N, int K) {
  __shared__ __align__(16) unsigned short As[128 * APITCH];
  __shared__ __align__(16) unsigned short Bs[128 * APITCH];
  int b  = blockIdx.z;
  int m0 = blockIdx.y * 128;
  int n0 = blockIdx.x * 128;
  const unsigned short* Xb = X + (size_t)b * N * K;
  int tid = threadIdx.x;
  int lane = tid & 63;
  int wave = tid >> 6;
  int wm = wave >> 1, wn = wave & 1;
  int quad = lane >> 4, l16 = lane & 15;

  f32x4 acc[4][4];
  f32x4 zero = {0.f, 0.f, 0.f, 0.f};
  for (int i = 0; i < 4; i++)
    for (int j = 0; j < 4; j++) acc[i][j] = zero;

  for (int k0 = 0; k0 < K; k0 += 32) {
    for (int i = 0; i < 2; i++) {
      int chunk = tid + 256 * i;          // 0..511
      int row = chunk >> 2;               // 0..127
      int kp  = (chunk & 3) * 8;          // 0,8,16,24
      f32x4 f0 = *(const f32x4*)&A[(size_t)(m0 + row) * K + k0 + kp];
      f32x4 f1 = *(const f32x4*)&A[(size_t)(m0 + row) * K + k0 + kp + 4];
      union { uint4 q; unsigned short s[8]; } ua;
      for (int j = 0; j < 4; j++) { ua.s[j] = f2bf(f0[j]); ua.s[j + 4] = f2bf(f1[j]); }
      *(uint4*)&As[row * APITCH + kp] = ua.q;
      *(uint4*)&Bs[row * APITCH + kp] =
          *(const uint4*)&Xb[(size_t)(n0 + row) * K + k0 + kp];
    }
    __syncthreads();
    bf16x8 af[4], bfr[4];
    for (int i = 0; i < 4; i++)
      af[i] = *(const bf16x8*)&As[(wm * 64 + i * 16 + l16) * APITCH + quad * 8];
    for (int j = 0; j < 4; j++)
      bfr[j] = *(const bf16x8*)&Bs[(wn * 64 + j * 16 + l16) * APITCH + quad * 8];
    for (int i = 0; i < 4; i++)
      for (int j = 0; j < 4; j++)
        acc[i][j] = __builtin_amdgcn_mfma_f32_16x16x32_bf16(af[i], bfr[j], acc[i][j], 0, 0, 0);
    __syncthreads();
  }

  // C/D layout: row = quad*4+reg, col = l16 (m89/m91-verified)
  for (int i = 0; i < 4; i++) {
    int gmb = m0 + wm * 64 + i * 16 + quad * 4;
    for (int j = 0; j < 4; j++) {
      int gn = n0 + wn * 64 + j * 16 + l16;
      for (int r = 0; r < 4; r++) {
        int gm = gmb + r;
        float v = acc[i][j][r];
        if (OUT_F32) {
          v += bias[gm];
          ((float*)Cout)[(size_t)b * M * N + (size_t)gm * N + gn] = v;
        } else {
          ((unsigned short*)Cout)[(size_t)b * M * N + (size_t)gm * N + gn] = f2bf(v);
        }
      }
    }
  }
}

// ---------------- l2norm rows of 1024 (q then k), 64 threads/row -------------
__global__ void l2norm_rows(unsigned short* __restrict__ q,
                            unsigned short* __restrict__ k, int rows) {
  int r = blockIdx.x;
  unsigned short* p = (r < rows) ? (q + (size_t)r * NPIX)
                                 : (k + (size_t)(r - rows) * NPIX);
  int lane = threadIdx.x;
  union { uint4 q4[2]; unsigned short s[16]; } u;
  u.q4[0] = *(const uint4*)&p[lane * 16];
  u.q4[1] = *(const uint4*)&p[lane * 16 + 8];
  float s = 0.f;
  for (int i = 0; i < 16; i++) { float f = bf2f(u.s[i]); s += f * f; }
  for (int off = 32; off > 0; off >>= 1) s += __shfl_down(s, off);
  s = __shfl(s, 0);
  float scale = 1.f / fmaxf(sqrtf(s), 1e-12f);
  for (int i = 0; i < 16; i++) u.s[i] = f2bf(bf2f(u.s[i]) * scale);
  *(uint4*)&p[lane * 16] = u.q4[0];
  *(uint4*)&p[lane * 16 + 8] = u.q4[1];
}

// ---------------- depthwise 3x3 per-channel stats (sum, sumsq) ---------------
__global__ void dw_stats(const float* __restrict__ x,
                         const float* __restrict__ wgt,
                         float* __restrict__ s1, float* __restrict__ s2) {
  int c = blockIdx.x, b = blockIdx.y;
  __shared__ __align__(16) float plane[NPIX];
  const float* xp = x + ((size_t)b * CCH + c) * NPIX;
  *(f32x4*)&plane[threadIdx.x * 4] = *(const f32x4*)&xp[threadIdx.x * 4];
  __syncthreads();
  float w[9];
  for (int i = 0; i < 9; i++) w[i] = wgt[c * 9 + i];
  float a1 = 0.f, a2 = 0.f;
  for (int pi = 0; pi < 4; pi++) {
    int p = threadIdx.x + pi * 256;
    int h = p >> 5, wc = p & 31;
    float v = 0.f;
    for (int dh = -1; dh <= 1; dh++)
      for (int dw = -1; dw <= 1; dw++) {
        int hh = h + dh, ww = wc + dw;
        if (hh >= 0 && hh < 32 && ww >= 0 && ww < 32)
          v += w[(dh + 1) * 3 + dw + 1] * plane[hh * 32 + ww];
      }
    a1 += v; a2 += v * v;
  }
  for (int off = 32; off > 0; off >>= 1) {
    a1 += __shfl_down(a1, off);
    a2 += __shfl_down(a2, off);
  }
  __shared__ float r1[4], r2[4];
  int wv = threadIdx.x >> 6;
  if ((threadIdx.x & 63) == 0) { r1[wv] = a1; r2[wv] = a2; }
  __syncthreads();
  if (threadIdx.x == 0) {
    atomicAdd(&s1[c], r1[0] + r1[1] + r1[2] + r1[3]);
    atomicAdd(&s2[c], r2[0] + r2[1] + r2[2] + r2[3]);
  }
}

// ---------------- gate: v *= SiLU(BN(conv(x))) -------------------------------
__global__ void gate_apply(const float* __restrict__ x,
                           const float* __restrict__ wgt,
                           const float* __restrict__ s1, const float* __restrict__ s2,
                           const float* __restrict__ gamma,
                           const float* __restrict__ beta,
                           unsigned short* __restrict__ v) {
  int c = blockIdx.x, b = blockIdx.y;
  __shared__ __align__(16) float plane[NPIX];
  size_t base = ((size_t)b * CCH + c) * NPIX;
  *(f32x4*)&plane[threadIdx.x * 4] = *(const f32x4*)&x[base + threadIdx.x * 4];
  __syncthreads();
  float w[9];
  for (int i = 0; i < 9; i++) w[i] = wgt[c * 9 + i];
  const float invn = 1.f / 32768.f;
  float mean = s1[c] * invn;
  float var = fmaxf(s2[c] * invn - mean * mean, 0.f);
  float rstd = rsqrtf(var + 1e-5f);
  float ga = gamma[c], be = beta[c];
  for (int pi = 0; pi < 4; pi++) {
    int p = threadIdx.x + pi * 256;
    int h = p >> 5, wc = p & 31;
    float val = 0.f;
    for (int dh = -1; dh <= 1; dh++)
      for (int dw = -1; dw <= 1; dw++) {
        int hh = h + dh, ww = wc + dw;
        if (hh >= 0 && hh < 32 && ww >= 0 && ww < 32)
          val += w[(dh + 1) * 3 + dw + 1] * plane[hh * 32 + ww];
      }
    float g = (val - mean) * rstd * ga + be;
    float sg = g / (1.f + expf(-g));      // SiLU
    v[base + p] = f2bf(bf2f(v[base + p]) * sg);
  }
}

// ---------------- attention per (b,h): S=QK^T, softmax, O=PV -----------------
// out may alias q (block consumes its own Q slice in phase 1 before writing O).
__launch_bounds__(256)
__global__ void attn_k(const unsigned short* __restrict__ q,
                       const unsigned short* __restrict__ k,
                       const unsigned short* __restrict__ v,
                       const float* __restrict__ temp,
                       unsigned short* __restrict__ out) {
  int bh = blockIdx.x;
  int b = bh >> 3, h = bh & 7;
  size_t base = ((size_t)b * CCH + h * 64) * NPIX;
  const unsigned short* Q = q + base;
  const unsigned short* K = k + base;
  const unsigned short* V = v + base;
  unsigned short* O = out + base;
  int tid = threadIdx.x, lane = tid & 63, wave = tid >> 6;
  int quad = lane >> 4, l16 = lane & 15;
  float tmp = temp[h];

  __shared__ __align__(16) float Sf[64][66];
  __shared__ __align__(16) unsigned short Ps[64][72];

  f32x4 zero = {0.f, 0.f, 0.f, 0.f};
  f32x4 acc[4];
  for (int j = 0; j < 4; j++) acc[j] = zero;
  for (int n0 = 0; n0 < NPIX; n0 += 32) {
    bf16x8 a = *(const bf16x8*)&Q[(size_t)(wave * 16 + l16) * NPIX + n0 + quad * 8];
    for (int j = 0; j < 4; j++) {
      bf16x8 bb = *(const bf16x8*)&K[(size_t)(j * 16 + l16) * NPIX + n0 + quad * 8];
      acc[j] = __builtin_amdgcn_mfma_f32_16x16x32_bf16(a, bb, acc[j], 0, 0, 0);
    }
  }
  for (int j = 0; j < 4; j++)
    for (int r = 0; r < 4; r++)
      Sf[wave * 16 + quad * 4 + r][j * 16 + l16] = acc[j][r] * tmp;
  __syncthreads();

  if (tid < 64) {
    float m = -1e30f;
    for (int e = 0; e < 64; e++) m = fmaxf(m, Sf[tid][e]);
    float s = 0.f;
    for (int e = 0; e < 64; e++) s += expf(Sf[tid][e] - m);
    float inv = 1.f / s;
    for (int e = 0; e < 64; e++) Ps[tid][e] = f2bf(expf(Sf[tid][e] - m) * inv);
  }
  __syncthreads();

  for (int nt = 0; nt < 16; nt++) {
    int n0 = wave * 256 + nt * 16;
    f32x4 oacc[4];
    for (int i = 0; i < 4; i++) oacc[i] = zero;
    for (int ks = 0; ks < 2; ks++) {
      bf16x8 bb;
      for (int jj = 0; jj < 8; jj++)
        bb[jj] = (short)V[(size_t)(ks * 32 + quad * 8 + jj) * NPIX + n0 + l16];
      for (int i = 0; i < 4; i++) {
        bf16x8 a = *(const bf16x8*)&Ps[i * 16 + l16][ks * 32 + quad * 8];
        oacc[i] = __builtin_amdgcn_mfma_f32_16x16x32_bf16(a, bb, oacc[i], 0, 0, 0);
      }
    }
    for (int i = 0; i < 4; i++)
      for (int r = 0; r < 4; r++)
        O[(size_t)(i * 16 + quad * 4 + r) * NPIX + n0 + l16] = f2bf(oacc[i][r]);
  }
}

// ---------------------------------------------------------------------------
extern "C" void kernel_launch(void* const* d_in, const int* in_sizes, int n_in,
                              void* d_out, int out_size, void* d_ws, size_t ws_size,
                              hipStream_t stream) {
  const float* x     = (const float*)d_in[0];
  const float* Wq    = (const float*)d_in[1];
  const float* Wk    = (const float*)d_in[2];
  const float* Wv    = (const float*)d_in[3];
  const float* dww   = (const float*)d_in[4];
  const float* gamma = (const float*)d_in[5];
  const float* beta  = (const float*)d_in[6];
  const float* temp  = (const float*)d_in[7];
  const float* Wp    = (const float*)d_in[8];
  const float* bp    = (const float*)d_in[9];
  float* out = (float*)d_out;   // reference output dtype is float32

  char* ws = (char*)d_ws;
  const size_t CHB = (size_t)BC * CCH * NPIX * 2;   // 8 MB per chunk buffer
  unsigned short* xT = (unsigned short*)(ws);           // [BC,N,C]
  unsigned short* qb = (unsigned short*)(ws + CHB);     // [BC,C,N]; reused as ao
  unsigned short* kb = (unsigned short*)(ws + 2 * CHB); // [BC,C,N]; reused as aoT
  unsigned short* vb = (unsigned short*)(ws + 3 * CHB);
  float* s1 = (float*)(ws + 4 * CHB);
  float* s2 = s1 + CCH;

  dim3 tb(32, 8);
  dim3 tgrid(NPIX / 32, CCH / 32, BC);
  dim3 ggrid(NPIX / 128, CCH / 128, BC);

  // batch-global BN stats first
  hipMemsetAsync(s1, 0, 2 * CCH * sizeof(float), stream);
  dw_stats<<<dim3(CCH, BATCH), 256, 0, stream>>>(x, dww, s1, s2);

  for (int b0 = 0; b0 < BATCH; b0 += BC) {
    const float* xc = x + (size_t)b0 * CCH * NPIX;
    float* outc = out + (size_t)b0 * CCH * NPIX;

    transpose_f2b<<<tgrid, tb, 0, stream>>>(xc, xT, CCH, NPIX);
    gemm_bt<false><<<ggrid, 256, 0, stream>>>(Wq, xT, qb, nullptr, CCH, NPIX, CCH);
    gemm_bt<false><<<ggrid, 256, 0, stream>>>(Wk, xT, kb, nullptr, CCH, NPIX, CCH);
    gemm_bt<false><<<ggrid, 256, 0, stream>>>(Wv, xT, vb, nullptr, CCH, NPIX, CCH);
    l2norm_rows<<<2 * BC * CCH, 64, 0, stream>>>(qb, kb, BC * CCH);
    gate_apply<<<dim3(CCH, BC), 256, 0, stream>>>(xc, dww, s1, s2, gamma, beta, vb);
    // attention: write O over the q buffer (safe; see kernel comment)
    attn_k<<<BC * HEADS, 256, 0, stream>>>(qb, kb, vb, temp, qb);
    // aoT into kb (kb dead after attn)
    transpose_b2b<<<tgrid, tb, 0, stream>>>(qb, kb, CCH, NPIX);
    gemm_bt<true><<<ggrid, 256, 0, stream>>>(Wp, kb, outc, bp, CCH, NPIX, CCH);
  }
}

// Round 4
// 353.947 us; speedup vs baseline: 2.1178x; 2.1178x over previous
//
#include <hip/hip_runtime.h>
#include <stdint.h>

#define BATCH 32
#define CCH   512
#define NPIX  1024
#define HEADS 8
#define QKV_M 1536   // q rows 0-511, k rows 512-1023, v rows 1024-1535

typedef short bf16x8 __attribute__((ext_vector_type(8)));
typedef float f32x4 __attribute__((ext_vector_type(4)));

__device__ inline float bf2f(unsigned short u) {
  union { float f; uint32_t i; } t; t.i = ((uint32_t)u) << 16; return t.f;
}
__device__ inline unsigned short f2bf(float f) {
  union { float f; uint32_t u; } t; t.f = f;
  uint32_t u = t.u;
  return (unsigned short)((u + 0x7FFFu + ((u >> 16) & 1u)) >> 16);
}

// ---------------- weights fp32 -> bf16 (Wq|Wk|Wv concat, Wp separate) --------
__global__ void convert_w(const float* __restrict__ Wq, const float* __restrict__ Wk,
                          const float* __restrict__ Wv, const float* __restrict__ Wp,
                          unsigned short* __restrict__ wcat,
                          unsigned short* __restrict__ wpb) {
  int i = (blockIdx.x * 256 + threadIdx.x) * 4;   // over CCH*CCH = 262144
  union { ushort4 u4; unsigned short s[4]; } o;
  f32x4 a;
  a = *(const f32x4*)&Wq[i];
  for (int j = 0; j < 4; j++) o.s[j] = f2bf(a[j]);
  *(ushort4*)&wcat[i] = o.u4;
  a = *(const f32x4*)&Wk[i];
  for (int j = 0; j < 4; j++) o.s[j] = f2bf(a[j]);
  *(ushort4*)&wcat[CCH * CCH + i] = o.u4;
  a = *(const f32x4*)&Wv[i];
  for (int j = 0; j < 4; j++) o.s[j] = f2bf(a[j]);
  *(ushort4*)&wcat[2 * CCH * CCH + i] = o.u4;
  a = *(const f32x4*)&Wp[i];
  for (int j = 0; j < 4; j++) o.s[j] = f2bf(a[j]);
  *(ushort4*)&wpb[i] = o.u4;
}

// ---------------- transpose fp32 [b,R,Cc] -> bf16 [b,Cc,R] -------------------
__global__ void transpose_f2b(const float* __restrict__ in,
                              unsigned short* __restrict__ out, int R, int Cc) {
  __shared__ float tile[32][33];
  int b = blockIdx.z;
  int c0 = blockIdx.x * 32;
  int r0 = blockIdx.y * 32;
  const float* inb = in + (size_t)b * R * Cc;
  unsigned short* outb = out + (size_t)b * R * Cc;
  int tx = threadIdx.x, ty = threadIdx.y;
  for (int i = 0; i < 4; i++) {
    int r = ty + i * 8;
    tile[r][tx] = inb[(size_t)(r0 + r) * Cc + c0 + tx];
  }
  __syncthreads();
  for (int i = 0; i < 4; i++) {
    int r = ty + i * 8;
    outb[(size_t)(c0 + r) * R + r0 + tx] = f2bf(tile[tx][r]);
  }
}

// ---------------- gemm_bt: C[b][m][n] = sum_k A[m][k]*X[b][n][k] -------------
// A [M,K] bf16 (weights); X [b,N,K] bf16. 128x128 tile, BK=32, 2x2 waves.
#define APITCH 40
template <bool OUT_F32>
__launch_bounds__(256)
__global__ void gemm_bt(const unsigned short* __restrict__ A,
                        const unsigned short* __restrict__ X,
                        void* __restrict__ Cout,
                        const float* __restrict__ bias,
                        int M, int N, int K) {
  __shared__ __align__(16) unsigned short As[128 * APITCH];
  __shared__ __align__(16) unsigned short Bs[128 * APITCH];
  int b  = blockIdx.z;
  int m0 = blockIdx.y * 128;
  int n0 = blockIdx.x * 128;
  const unsigned short* Xb = X + (size_t)b * N * K;
  int tid = threadIdx.x;
  int lane = tid & 63;
  int wave = tid >> 6;
  int wm = wave >> 1, wn = wave & 1;
  int quad = lane >> 4, l16 = lane & 15;

  f32x4 acc[4][4];
  f32x4 zero = {0.f, 0.f, 0.f, 0.f};
  for (int i = 0; i < 4; i++)
    for (int j = 0; j < 4; j++) acc[i][j] = zero;

  for (int k0 = 0; k0 < K; k0 += 32) {
    for (int i = 0; i < 2; i++) {
      int chunk = tid + 256 * i;          // 0..511
      int row = chunk >> 2;               // 0..127
      int kp  = (chunk & 3) * 8;          // 0,8,16,24
      *(uint4*)&As[row * APITCH + kp] =
          *(const uint4*)&A[(size_t)(m0 + row) * K + k0 + kp];
      *(uint4*)&Bs[row * APITCH + kp] =
          *(const uint4*)&Xb[(size_t)(n0 + row) * K + k0 + kp];
    }
    __syncthreads();
    bf16x8 af[4], bfr[4];
    for (int i = 0; i < 4; i++)
      af[i] = *(const bf16x8*)&As[(wm * 64 + i * 16 + l16) * APITCH + quad * 8];
    for (int j = 0; j < 4; j++)
      bfr[j] = *(const bf16x8*)&Bs[(wn * 64 + j * 16 + l16) * APITCH + quad * 8];
    for (int i = 0; i < 4; i++)
      for (int j = 0; j < 4; j++)
        acc[i][j] = __builtin_amdgcn_mfma_f32_16x16x32_bf16(af[i], bfr[j], acc[i][j], 0, 0, 0);
    __syncthreads();
  }

  // C/D layout: row = quad*4+reg, col = l16
  for (int i = 0; i < 4; i++) {
    int gmb = m0 + wm * 64 + i * 16 + quad * 4;
    for (int j = 0; j < 4; j++) {
      int gn = n0 + wn * 64 + j * 16 + l16;
      for (int r = 0; r < 4; r++) {
        int gm = gmb + r;
        float v = acc[i][j][r];
        if (OUT_F32) {
          v += bias[gm];
          ((float*)Cout)[(size_t)b * M * N + (size_t)gm * N + gn] = v;
        } else {
          ((unsigned short*)Cout)[(size_t)b * M * N + (size_t)gm * N + gn] = f2bf(v);
        }
      }
    }
  }
}

// ---------------- l2norm q,k rows in qkv buffer; 4 rows per block ------------
__global__ void l2norm_qk(unsigned short* __restrict__ qkv, int nb) {
  int id = blockIdx.x * 4 + (threadIdx.x >> 6);
  int lane = threadIdx.x & 63;
  int total = nb * CCH;
  int isK = id >= total;
  int r = isK ? id - total : id;
  int b = r >> 9, c = r & 511;
  unsigned short* p = qkv + ((size_t)b * QKV_M + (isK ? CCH : 0) + c) * NPIX;
  union { uint4 q4[2]; unsigned short s[16]; } u;
  u.q4[0] = *(const uint4*)&p[lane * 16];
  u.q4[1] = *(const uint4*)&p[lane * 16 + 8];
  float s = 0.f;
  for (int i = 0; i < 16; i++) { float f = bf2f(u.s[i]); s += f * f; }
  for (int off = 32; off > 0; off >>= 1) s += __shfl_down(s, off);
  s = __shfl(s, 0);
  float scale = 1.f / fmaxf(sqrtf(s), 1e-12f);
  for (int i = 0; i < 16; i++) u.s[i] = f2bf(bf2f(u.s[i]) * scale);
  *(uint4*)&p[lane * 16] = u.q4[0];
  *(uint4*)&p[lane * 16 + 8] = u.q4[1];
}

// ---------------- depthwise 3x3 per-channel stats (sum, sumsq) ---------------
__global__ void dw_stats(const float* __restrict__ x,
                         const float* __restrict__ wgt,
                         float* __restrict__ s1, float* __restrict__ s2) {
  int c = blockIdx.x, b = blockIdx.y;
  __shared__ __align__(16) float plane[NPIX];
  const float* xp = x + ((size_t)b * CCH + c) * NPIX;
  *(f32x4*)&plane[threadIdx.x * 4] = *(const f32x4*)&xp[threadIdx.x * 4];
  __syncthreads();
  float w[9];
  for (int i = 0; i < 9; i++) w[i] = wgt[c * 9 + i];
  float a1 = 0.f, a2 = 0.f;
  for (int pi = 0; pi < 4; pi++) {
    int p = threadIdx.x + pi * 256;
    int h = p >> 5, wc = p & 31;
    float v = 0.f;
    for (int dh = -1; dh <= 1; dh++)
      for (int dw = -1; dw <= 1; dw++) {
        int hh = h + dh, ww = wc + dw;
        if (hh >= 0 && hh < 32 && ww >= 0 && ww < 32)
          v += w[(dh + 1) * 3 + dw + 1] * plane[hh * 32 + ww];
      }
    a1 += v; a2 += v * v;
  }
  for (int off = 32; off > 0; off >>= 1) {
    a1 += __shfl_down(a1, off);
    a2 += __shfl_down(a2, off);
  }
  __shared__ float r1[4], r2[4];
  int wv = threadIdx.x >> 6;
  if ((threadIdx.x & 63) == 0) { r1[wv] = a1; r2[wv] = a2; }
  __syncthreads();
  if (threadIdx.x == 0) {
    atomicAdd(&s1[c], r1[0] + r1[1] + r1[2] + r1[3]);
    atomicAdd(&s2[c], r2[0] + r2[1] + r2[2] + r2[3]);
  }
}

// ---------------- gate: v (rows 1024..1535 of qkv) *= SiLU(BN(conv(x))) ------
__global__ void gate_apply(const float* __restrict__ x,
                           const float* __restrict__ wgt,
                           const float* __restrict__ s1, const float* __restrict__ s2,
                           const float* __restrict__ gamma,
                           const float* __restrict__ beta,
                           unsigned short* __restrict__ qkv) {
  int c = blockIdx.x, b = blockIdx.y;
  __shared__ __align__(16) float plane[NPIX];
  const float* xp = x + ((size_t)b * CCH + c) * NPIX;
  unsigned short* vp = qkv + ((size_t)b * QKV_M + 2 * CCH + c) * NPIX;
  *(f32x4*)&plane[threadIdx.x * 4] = *(const f32x4*)&xp[threadIdx.x * 4];
  __syncthreads();
  float w[9];
  for (int i = 0; i < 9; i++) w[i] = wgt[c * 9 + i];
  const float invn = 1.f / 32768.f;
  float mean = s1[c] * invn;
  float var = fmaxf(s2[c] * invn - mean * mean, 0.f);
  float rstd = rsqrtf(var + 1e-5f);
  float ga = gamma[c], be = beta[c];
  for (int pi = 0; pi < 4; pi++) {
    int p = threadIdx.x + pi * 256;
    int h = p >> 5, wc = p & 31;
    float val = 0.f;
    for (int dh = -1; dh <= 1; dh++)
      for (int dw = -1; dw <= 1; dw++) {
        int hh = h + dh, ww = wc + dw;
        if (hh >= 0 && hh < 32 && ww >= 0 && ww < 32)
          val += w[(dh + 1) * 3 + dw + 1] * plane[hh * 32 + ww];
      }
    float g = (val - mean) * rstd * ga + be;
    float sg = g / (1.f + __expf(-g));      // SiLU
    vp[p] = f2bf(bf2f(vp[p]) * sg);
  }
}

// ---------------- attention per (b,h): S=QK^T, softmax, O^T = V^T P^T --------
// Writes aoT [b, N, C] directly (no separate transpose needed).
__launch_bounds__(256)
__global__ void attn_k(const unsigned short* __restrict__ qkv,
                       const float* __restrict__ temp,
                       unsigned short* __restrict__ aoT) {
  int bh = blockIdx.x;
  int b = bh >> 3, h = bh & 7;
  const unsigned short* Q = qkv + ((size_t)b * QKV_M + h * 64) * NPIX;
  const unsigned short* K = Q + (size_t)CCH * NPIX;
  const unsigned short* V = Q + (size_t)2 * CCH * NPIX;
  unsigned short* Ob = aoT + (size_t)b * NPIX * CCH + h * 64;
  int tid = threadIdx.x, lane = tid & 63, wave = tid >> 6;
  int quad = lane >> 4, l16 = lane & 15;

  __shared__ __align__(16) float Sf[64][65];
  __shared__ __align__(16) unsigned short Ps[64][72];
  __shared__ __align__(16) unsigned short Vt[4][16][72];
  __shared__ float redm[4][64], reds[4][64];

  // ---- Phase 1: S[d][e] = sum_n Q[d][n]K[e][n]; wave owns d-rows [16w,16w+16)
  f32x4 zero = {0.f, 0.f, 0.f, 0.f};
  f32x4 acc[4];
  for (int j = 0; j < 4; j++) acc[j] = zero;
  for (int n0 = 0; n0 < NPIX; n0 += 32) {
    bf16x8 a = *(const bf16x8*)&Q[(size_t)(wave * 16 + l16) * NPIX + n0 + quad * 8];
    for (int j = 0; j < 4; j++) {
      bf16x8 bb = *(const bf16x8*)&K[(size_t)(j * 16 + l16) * NPIX + n0 + quad * 8];
      acc[j] = __builtin_amdgcn_mfma_f32_16x16x32_bf16(a, bb, acc[j], 0, 0, 0);
    }
  }
  float tmp = temp[h];
  for (int j = 0; j < 4; j++)
    for (int r = 0; r < 4; r++)
      Sf[wave * 16 + quad * 4 + r][j * 16 + l16] = acc[j][r] * tmp;
  __syncthreads();

  // ---- softmax over e, parallel: 256 threads = 64 rows x 4 col-segments
  {
    int row = tid & 63, seg = tid >> 6;
    float pm = -1e30f;
    for (int i = 0; i < 16; i++) pm = fmaxf(pm, Sf[row][seg * 16 + i]);
    redm[seg][row] = pm;
    __syncthreads();
    float m = fmaxf(fmaxf(redm[0][row], redm[1][row]),
                    fmaxf(redm[2][row], redm[3][row]));
    float ps = 0.f;
    for (int i = 0; i < 16; i++) ps += __expf(Sf[row][seg * 16 + i] - m);
    reds[seg][row] = ps;
    __syncthreads();
    float inv = 1.f / (reds[0][row] + reds[1][row] + reds[2][row] + reds[3][row]);
    for (int i = 0; i < 16; i++)
      Ps[row][seg * 16 + i] = f2bf(__expf(Sf[row][seg * 16 + i] - m) * inv);
  }
  __syncthreads();

  // ---- preload P fragments (B-operand: rows d, k = e)
  bf16x8 Pf[4][2];
  for (int j = 0; j < 4; j++)
    for (int ks = 0; ks < 2; ks++)
      Pf[j][ks] = *(const bf16x8*)&Ps[j * 16 + l16][ks * 32 + quad * 8];

  // ---- Phase 2: O^T[n][d] = sum_e V^T[n][e] P[d][e]; wave owns n in [256w,..)
  int e1 = lane >> 1, noff = (lane & 1) * 8;
  for (int nt = 0; nt < 16; nt++) {
    int n0 = wave * 256 + nt * 16;
    union { uint4 q; unsigned short s[8]; } g0, g1;
    g0.q = *(const uint4*)&V[(size_t)e1 * NPIX + n0 + noff];
    g1.q = *(const uint4*)&V[(size_t)(e1 + 32) * NPIX + n0 + noff];
    for (int jj = 0; jj < 8; jj++) {
      Vt[wave][noff + jj][e1]      = g0.s[jj];
      Vt[wave][noff + jj][e1 + 32] = g1.s[jj];
    }
    // HW processes a wave's LDS ops in order; fence compiler reordering only.
    __builtin_amdgcn_sched_barrier(0);
    bf16x8 Af0 = *(const bf16x8*)&Vt[wave][l16][quad * 8];
    bf16x8 Af1 = *(const bf16x8*)&Vt[wave][l16][32 + quad * 8];
    f32x4 oacc[4];
    for (int j = 0; j < 4; j++) {
      oacc[j] = __builtin_amdgcn_mfma_f32_16x16x32_bf16(Af0, Pf[j][0], zero, 0, 0, 0);
      oacc[j] = __builtin_amdgcn_mfma_f32_16x16x32_bf16(Af1, Pf[j][1], oacc[j], 0, 0, 0);
    }
    __builtin_amdgcn_sched_barrier(0);
    for (int j = 0; j < 4; j++)
      for (int r = 0; r < 4; r++)
        Ob[(size_t)(n0 + quad * 4 + r) * CCH + j * 16 + l16] = f2bf(oacc[j][r]);
  }
}

// ---------------------------------------------------------------------------
extern "C" void kernel_launch(void* const* d_in, const int* in_sizes, int n_in,
                              void* d_out, int out_size, void* d_ws, size_t ws_size,
                              hipStream_t stream) {
  const float* x     = (const float*)d_in[0];
  const float* Wq    = (const float*)d_in[1];
  const float* Wk    = (const float*)d_in[2];
  const float* Wv    = (const float*)d_in[3];
  const float* dww   = (const float*)d_in[4];
  const float* gamma = (const float*)d_in[5];
  const float* beta  = (const float*)d_in[6];
  const float* temp  = (const float*)d_in[7];
  const float* Wp    = (const float*)d_in[8];
  const float* bp    = (const float*)d_in[9];
  float* out = (float*)d_out;

  char* ws = (char*)d_ws;
  unsigned short* wcat = (unsigned short*)ws;             // [1536,512] bf16
  unsigned short* wpb  = wcat + (size_t)QKV_M * CCH;      // [512,512] bf16
  float* s1 = (float*)(wpb + (size_t)CCH * CCH);
  float* s2 = s1 + CCH;
  char* dyn = (char*)(s2 + CCH);
  size_t fixed = (size_t)(dyn - ws);
  size_t per_b = ((size_t)NPIX * CCH + (size_t)QKV_M * NPIX) * 2;  // 4 MB/batch
  int BC = BATCH;
  while (BC > 1 && fixed + (size_t)BC * per_b > ws_size) BC >>= 1;
  unsigned short* xT  = (unsigned short*)dyn;                  // [BC,N,C]; reused as aoT
  unsigned short* qkv = xT + (size_t)BC * NPIX * CCH;          // [BC,1536,N]

  convert_w<<<CCH * CCH / 1024, 256, 0, stream>>>(Wq, Wk, Wv, Wp, wcat, wpb);
  hipMemsetAsync(s1, 0, 2 * CCH * sizeof(float), stream);
  dw_stats<<<dim3(CCH, BATCH), 256, 0, stream>>>(x, dww, s1, s2);

  for (int b0 = 0; b0 < BATCH; b0 += BC) {
    const float* xc = x + (size_t)b0 * CCH * NPIX;
    float* outc = out + (size_t)b0 * CCH * NPIX;
    transpose_f2b<<<dim3(NPIX / 32, CCH / 32, BC), dim3(32, 8), 0, stream>>>(
        xc, xT, CCH, NPIX);
    gemm_bt<false><<<dim3(NPIX / 128, QKV_M / 128, BC), 256, 0, stream>>>(
        wcat, xT, qkv, nullptr, QKV_M, NPIX, CCH);
    l2norm_qk<<<BC * 256, 256, 0, stream>>>(qkv, BC);
    gate_apply<<<dim3(CCH, BC), 256, 0, stream>>>(xc, dww, s1, s2, gamma, beta, qkv);
    attn_k<<<BC * HEADS, 256, 0, stream>>>(qkv, temp, xT);   // aoT overwrites xT
    gemm_bt<true><<<dim3(NPIX / 128, CCH / 128, BC), 256, 0, stream>>>(
        wpb, xT, outc, bp, CCH, NPIX, CCH);
  }
}

// Round 5
// 350.918 us; speedup vs baseline: 2.1361x; 1.0086x over previous
//
#include <hip/hip_runtime.h>
#include <stdint.h>

#define BATCH 32
#define CCH   512
#define NPIX  1024
#define HEADS 8
#define QKV_M 1536   // q rows 0-511, k rows 512-1023, v rows 1024-1535

typedef short bf16x8 __attribute__((ext_vector_type(8)));
typedef float f32x4 __attribute__((ext_vector_type(4)));

__device__ inline float bf2f(unsigned short u) {
  union { float f; uint32_t i; } t; t.i = ((uint32_t)u) << 16; return t.f;
}
__device__ inline unsigned short f2bf(float f) {
  union { float f; uint32_t u; } t; t.f = f;
  uint32_t u = t.u;
  return (unsigned short)((u + 0x7FFFu + ((u >> 16) & 1u)) >> 16);
}

// async global->LDS, 16B per lane; LDS dest = wave-uniform base + lane*16
__device__ inline void gl_lds16(const unsigned short* g, unsigned short* l) {
  __builtin_amdgcn_global_load_lds(
      (const __attribute__((address_space(1))) uint32_t*)g,
      (__attribute__((address_space(3))) uint32_t*)l, 16, 0, 0);
}

// ---------------- weights fp32 -> bf16 (Wq|Wk|Wv concat, Wp separate) --------
__global__ void convert_w(const float* __restrict__ Wq, const float* __restrict__ Wk,
                          const float* __restrict__ Wv, const float* __restrict__ Wp,
                          unsigned short* __restrict__ wcat,
                          unsigned short* __restrict__ wpb) {
  int i = (blockIdx.x * 256 + threadIdx.x) * 4;   // over CCH*CCH = 262144
  union { ushort4 u4; unsigned short s[4]; } o;
  f32x4 a;
  a = *(const f32x4*)&Wq[i];
  for (int j = 0; j < 4; j++) o.s[j] = f2bf(a[j]);
  *(ushort4*)&wcat[i] = o.u4;
  a = *(const f32x4*)&Wk[i];
  for (int j = 0; j < 4; j++) o.s[j] = f2bf(a[j]);
  *(ushort4*)&wcat[CCH * CCH + i] = o.u4;
  a = *(const f32x4*)&Wv[i];
  for (int j = 0; j < 4; j++) o.s[j] = f2bf(a[j]);
  *(ushort4*)&wcat[2 * CCH * CCH + i] = o.u4;
  a = *(const f32x4*)&Wp[i];
  for (int j = 0; j < 4; j++) o.s[j] = f2bf(a[j]);
  *(ushort4*)&wpb[i] = o.u4;
}

// ---------------- transpose fp32 [b,R,Cc] -> bf16 [b,Cc,R] -------------------
__global__ void transpose_f2b(const float* __restrict__ in,
                              unsigned short* __restrict__ out, int R, int Cc) {
  __shared__ float tile[32][33];
  int b = blockIdx.z;
  int c0 = blockIdx.x * 32;
  int r0 = blockIdx.y * 32;
  const float* inb = in + (size_t)b * R * Cc;
  unsigned short* outb = out + (size_t)b * R * Cc;
  int tx = threadIdx.x, ty = threadIdx.y;
  for (int i = 0; i < 4; i++) {
    int r = ty + i * 8;
    tile[r][tx] = inb[(size_t)(r0 + r) * Cc + c0 + tx];
  }
  __syncthreads();
  for (int i = 0; i < 4; i++) {
    int r = ty + i * 8;
    outb[(size_t)(c0 + r) * R + r0 + tx] = f2bf(tile[tx][r]);
  }
}

// ---------------- gemm_bt: C[b][m][n] = sum_k A[m][k]*X[b][n][k] -------------
// A [M,K] bf16 (weights); X [b,N,K] bf16. 128x128 tile, BK=32, 2x2 waves.
// m97 structure: global_load_lds width=16 staging, contiguous pitch-32 LDS.
template <bool OUT_F32>
__launch_bounds__(256)
__global__ void gemm_bt(const unsigned short* __restrict__ A,
                        const unsigned short* __restrict__ X,
                        void* __restrict__ Cout,
                        const float* __restrict__ bias,
                        int M, int N, int K) {
  __shared__ __align__(16) unsigned short As[128 * 32];
  __shared__ __align__(16) unsigned short Bs[128 * 32];
  int b  = blockIdx.z;
  int m0 = blockIdx.y * 128;
  int n0 = blockIdx.x * 128;
  const unsigned short* Xb = X + (size_t)b * N * K;
  int tid = threadIdx.x;
  int lane = tid & 63;
  int wave = tid >> 6;
  int wm = wave >> 1, wn = wave & 1;
  int quad = lane >> 4, l16 = lane & 15;

  f32x4 acc[4][4];
  f32x4 zero = {0.f, 0.f, 0.f, 0.f};
  for (int i = 0; i < 4; i++)
    for (int j = 0; j < 4; j++) acc[i][j] = zero;

  // staging addressing: load (wave*2+i) covers tile rows [wave*32+i*16, +16),
  // lane -> row += lane>>2, k-offset (lane&3)*8 shorts; LDS = base + lane*16B.
  int srow = wave * 32 + (lane >> 2);
  int skp  = (lane & 3) * 8;
  const unsigned short* Ag = A  + (size_t)(m0 + srow) * K + skp;
  const unsigned short* Xg = Xb + (size_t)(n0 + srow) * K + skp;
  unsigned short* Al = &As[wave * 1024];
  unsigned short* Bl = &Bs[wave * 1024];

  for (int k0 = 0; k0 < K; k0 += 32) {
    gl_lds16(Ag + k0,            Al);
    gl_lds16(Ag + 16 * K + k0,   Al + 512);
    gl_lds16(Xg + k0,            Bl);
    gl_lds16(Xg + 16 * K + k0,   Bl + 512);
    __syncthreads();
    bf16x8 af[4], bfr[4];
    for (int i = 0; i < 4; i++)
      af[i] = *(const bf16x8*)&As[(wm * 64 + i * 16 + l16) * 32 + quad * 8];
    for (int j = 0; j < 4; j++)
      bfr[j] = *(const bf16x8*)&Bs[(wn * 64 + j * 16 + l16) * 32 + quad * 8];
    for (int i = 0; i < 4; i++)
      for (int j = 0; j < 4; j++)
        acc[i][j] = __builtin_amdgcn_mfma_f32_16x16x32_bf16(af[i], bfr[j], acc[i][j], 0, 0, 0);
    __syncthreads();
  }

  // C/D layout: row = quad*4+reg, col = l16
  for (int i = 0; i < 4; i++) {
    int gmb = m0 + wm * 64 + i * 16 + quad * 4;
    for (int j = 0; j < 4; j++) {
      int gn = n0 + wn * 64 + j * 16 + l16;
      for (int r = 0; r < 4; r++) {
        int gm = gmb + r;
        float v = acc[i][j][r];
        if (OUT_F32) {
          v += bias[gm];
          ((float*)Cout)[(size_t)b * M * N + (size_t)gm * N + gn] = v;
        } else {
          ((unsigned short*)Cout)[(size_t)b * M * N + (size_t)gm * N + gn] = f2bf(v);
        }
      }
    }
  }
}

// ---------------- l2norm q,k rows in qkv buffer; 4 rows per block ------------
__global__ void l2norm_qk(unsigned short* __restrict__ qkv, int nb) {
  int id = blockIdx.x * 4 + (threadIdx.x >> 6);
  int lane = threadIdx.x & 63;
  int total = nb * CCH;
  int isK = id >= total;
  int r = isK ? id - total : id;
  int b = r >> 9, c = r & 511;
  unsigned short* p = qkv + ((size_t)b * QKV_M + (isK ? CCH : 0) + c) * NPIX;
  union { uint4 q4[2]; unsigned short s[16]; } u;
  u.q4[0] = *(const uint4*)&p[lane * 16];
  u.q4[1] = *(const uint4*)&p[lane * 16 + 8];
  float s = 0.f;
  for (int i = 0; i < 16; i++) { float f = bf2f(u.s[i]); s += f * f; }
  for (int off = 32; off > 0; off >>= 1) s += __shfl_down(s, off);
  s = __shfl(s, 0);
  float scale = 1.f / fmaxf(sqrtf(s), 1e-12f);
  for (int i = 0; i < 16; i++) u.s[i] = f2bf(bf2f(u.s[i]) * scale);
  *(uint4*)&p[lane * 16] = u.q4[0];
  *(uint4*)&p[lane * 16 + 8] = u.q4[1];
}

// ---------------- depthwise 3x3 per-channel stats (sum, sumsq) ---------------
__global__ void dw_stats(const float* __restrict__ x,
                         const float* __restrict__ wgt,
                         float* __restrict__ s1, float* __restrict__ s2) {
  int c = blockIdx.x, b = blockIdx.y;
  __shared__ __align__(16) float plane[NPIX];
  const float* xp = x + ((size_t)b * CCH + c) * NPIX;
  *(f32x4*)&plane[threadIdx.x * 4] = *(const f32x4*)&xp[threadIdx.x * 4];
  __syncthreads();
  float w[9];
  for (int i = 0; i < 9; i++) w[i] = wgt[c * 9 + i];
  float a1 = 0.f, a2 = 0.f;
  for (int pi = 0; pi < 4; pi++) {
    int p = threadIdx.x + pi * 256;
    int h = p >> 5, wc = p & 31;
    float v = 0.f;
    for (int dh = -1; dh <= 1; dh++)
      for (int dw = -1; dw <= 1; dw++) {
        int hh = h + dh, ww = wc + dw;
        if (hh >= 0 && hh < 32 && ww >= 0 && ww < 32)
          v += w[(dh + 1) * 3 + dw + 1] * plane[hh * 32 + ww];
      }
    a1 += v; a2 += v * v;
  }
  for (int off = 32; off > 0; off >>= 1) {
    a1 += __shfl_down(a1, off);
    a2 += __shfl_down(a2, off);
  }
  __shared__ float r1[4], r2[4];
  int wv = threadIdx.x >> 6;
  if ((threadIdx.x & 63) == 0) { r1[wv] = a1; r2[wv] = a2; }
  __syncthreads();
  if (threadIdx.x == 0) {
    atomicAdd(&s1[c], r1[0] + r1[1] + r1[2] + r1[3]);
    atomicAdd(&s2[c], r2[0] + r2[1] + r2[2] + r2[3]);
  }
}

// ---------------- gate: v (rows 1024..1535 of qkv) *= SiLU(BN(conv(x))) ------
__global__ void gate_apply(const float* __restrict__ x,
                           const float* __restrict__ wgt,
                           const float* __restrict__ s1, const float* __restrict__ s2,
                           const float* __restrict__ gamma,
                           const float* __restrict__ beta,
                           unsigned short* __restrict__ qkv) {
  int c = blockIdx.x, b = blockIdx.y;
  __shared__ __align__(16) float plane[NPIX];
  const float* xp = x + ((size_t)b * CCH + c) * NPIX;
  unsigned short* vp = qkv + ((size_t)b * QKV_M + 2 * CCH + c) * NPIX;
  *(f32x4*)&plane[threadIdx.x * 4] = *(const f32x4*)&xp[threadIdx.x * 4];
  __syncthreads();
  float w[9];
  for (int i = 0; i < 9; i++) w[i] = wgt[c * 9 + i];
  const float invn = 1.f / 32768.f;
  float mean = s1[c] * invn;
  float var = fmaxf(s2[c] * invn - mean * mean, 0.f);
  float rstd = rsqrtf(var + 1e-5f);
  float ga = gamma[c], be = beta[c];
  for (int pi = 0; pi < 4; pi++) {
    int p = threadIdx.x + pi * 256;
    int h = p >> 5, wc = p & 31;
    float val = 0.f;
    for (int dh = -1; dh <= 1; dh++)
      for (int dw = -1; dw <= 1; dw++) {
        int hh = h + dh, ww = wc + dw;
        if (hh >= 0 && hh < 32 && ww >= 0 && ww < 32)
          val += w[(dh + 1) * 3 + dw + 1] * plane[hh * 32 + ww];
      }
    float g = (val - mean) * rstd * ga + be;
    float sg = g / (1.f + __expf(-g));      // SiLU
    vp[p] = f2bf(bf2f(vp[p]) * sg);
  }
}

// ---------------- attention per (b,h): S=QK^T, softmax, O^T = V^T P^T --------
// Writes aoT [b, N, C] directly (no separate transpose needed).
__launch_bounds__(256)
__global__ void attn_k(const unsigned short* __restrict__ qkv,
                       const float* __restrict__ temp,
                       unsigned short* __restrict__ aoT) {
  int bh = blockIdx.x;
  int b = bh >> 3, h = bh & 7;
  const unsigned short* Q = qkv + ((size_t)b * QKV_M + h * 64) * NPIX;
  const unsigned short* K = Q + (size_t)CCH * NPIX;
  const unsigned short* V = Q + (size_t)2 * CCH * NPIX;
  unsigned short* Ob = aoT + (size_t)b * NPIX * CCH + h * 64;
  int tid = threadIdx.x, lane = tid & 63, wave = tid >> 6;
  int quad = lane >> 4, l16 = lane & 15;

  __shared__ __align__(16) float Sf[64][65];
  __shared__ __align__(16) unsigned short Ps[64][72];
  __shared__ __align__(16) unsigned short Vt[4][16][72];
  __shared__ float redm[4][64], reds[4][64];

  // ---- Phase 1: S[d][e] = sum_n Q[d][n]K[e][n]; wave owns d-rows [16w,16w+16)
  f32x4 zero = {0.f, 0.f, 0.f, 0.f};
  f32x4 acc[4];
  for (int j = 0; j < 4; j++) acc[j] = zero;
  for (int n0 = 0; n0 < NPIX; n0 += 32) {
    bf16x8 a = *(const bf16x8*)&Q[(size_t)(wave * 16 + l16) * NPIX + n0 + quad * 8];
    for (int j = 0; j < 4; j++) {
      bf16x8 bb = *(const bf16x8*)&K[(size_t)(j * 16 + l16) * NPIX + n0 + quad * 8];
      acc[j] = __builtin_amdgcn_mfma_f32_16x16x32_bf16(a, bb, acc[j], 0, 0, 0);
    }
  }
  float tmp = temp[h];
  for (int j = 0; j < 4; j++)
    for (int r = 0; r < 4; r++)
      Sf[wave * 16 + quad * 4 + r][j * 16 + l16] = acc[j][r] * tmp;
  __syncthreads();

  // ---- softmax over e, parallel: 256 threads = 64 rows x 4 col-segments
  {
    int row = tid & 63, seg = tid >> 6;
    float pm = -1e30f;
    for (int i = 0; i < 16; i++) pm = fmaxf(pm, Sf[row][seg * 16 + i]);
    redm[seg][row] = pm;
    __syncthreads();
    float m = fmaxf(fmaxf(redm[0][row], redm[1][row]),
                    fmaxf(redm[2][row], redm[3][row]));
    float ps = 0.f;
    for (int i = 0; i < 16; i++) ps += __expf(Sf[row][seg * 16 + i] - m);
    reds[seg][row] = ps;
    __syncthreads();
    float inv = 1.f / (reds[0][row] + reds[1][row] + reds[2][row] + reds[3][row]);
    for (int i = 0; i < 16; i++)
      Ps[row][seg * 16 + i] = f2bf(__expf(Sf[row][seg * 16 + i] - m) * inv);
  }
  __syncthreads();

  // ---- preload P fragments (B-operand: rows d, k = e)
  bf16x8 Pf[4][2];
  for (int j = 0; j < 4; j++)
    for (int ks = 0; ks < 2; ks++)
      Pf[j][ks] = *(const bf16x8*)&Ps[j * 16 + l16][ks * 32 + quad * 8];

  // ---- Phase 2: O^T[n][d] = sum_e V^T[n][e] P[d][e]; wave owns n in [256w,..)
  int e1 = lane >> 1, noff = (lane & 1) * 8;
  for (int nt = 0; nt < 16; nt++) {
    int n0 = wave * 256 + nt * 16;
    union { uint4 q; unsigned short s[8]; } g0, g1;
    g0.q = *(const uint4*)&V[(size_t)e1 * NPIX + n0 + noff];
    g1.q = *(const uint4*)&V[(size_t)(e1 + 32) * NPIX + n0 + noff];
    for (int jj = 0; jj < 8; jj++) {
      Vt[wave][noff + jj][e1]      = g0.s[jj];
      Vt[wave][noff + jj][e1 + 32] = g1.s[jj];
    }
    // HW processes a wave's LDS ops in order; fence compiler reordering only.
    __builtin_amdgcn_sched_barrier(0);
    bf16x8 Af0 = *(const bf16x8*)&Vt[wave][l16][quad * 8];
    bf16x8 Af1 = *(const bf16x8*)&Vt[wave][l16][32 + quad * 8];
    f32x4 oacc[4];
    for (int j = 0; j < 4; j++) {
      oacc[j] = __builtin_amdgcn_mfma_f32_16x16x32_bf16(Af0, Pf[j][0], zero, 0, 0, 0);
      oacc[j] = __builtin_amdgcn_mfma_f32_16x16x32_bf16(Af1, Pf[j][1], oacc[j], 0, 0, 0);
    }
    __builtin_amdgcn_sched_barrier(0);
    for (int j = 0; j < 4; j++)
      for (int r = 0; r < 4; r++)
        Ob[(size_t)(n0 + quad * 4 + r) * CCH + j * 16 + l16] = f2bf(oacc[j][r]);
  }
}

// ---------------------------------------------------------------------------
extern "C" void kernel_launch(void* const* d_in, const int* in_sizes, int n_in,
                              void* d_out, int out_size, void* d_ws, size_t ws_size,
                              hipStream_t stream) {
  const float* x     = (const float*)d_in[0];
  const float* Wq    = (const float*)d_in[1];
  const float* Wk    = (const float*)d_in[2];
  const float* Wv    = (const float*)d_in[3];
  const float* dww   = (const float*)d_in[4];
  const float* gamma = (const float*)d_in[5];
  const float* beta  = (const float*)d_in[6];
  const float* temp  = (const float*)d_in[7];
  const float* Wp    = (const float*)d_in[8];
  const float* bp    = (const float*)d_in[9];
  float* out = (float*)d_out;

  char* ws = (char*)d_ws;
  unsigned short* wcat = (unsigned short*)ws;             // [1536,512] bf16
  unsigned short* wpb  = wcat + (size_t)QKV_M * CCH;      // [512,512] bf16
  float* s1 = (float*)(wpb + (size_t)CCH * CCH);
  float* s2 = s1 + CCH;
  char* dyn = (char*)(s2 + CCH);
  size_t fixed = (size_t)(dyn - ws);
  size_t per_b = ((size_t)NPIX * CCH + (size_t)QKV_M * NPIX) * 2;  // 4 MB/batch
  int BC = BATCH;
  while (BC > 1 && fixed + (size_t)BC * per_b > ws_size) BC >>= 1;
  unsigned short* xT  = (unsigned short*)dyn;                  // [BC,N,C]; reused as aoT
  unsigned short* qkv = xT + (size_t)BC * NPIX * CCH;          // [BC,1536,N]

  convert_w<<<CCH * CCH / 1024, 256, 0, stream>>>(Wq, Wk, Wv, Wp, wcat, wpb);
  hipMemsetAsync(s1, 0, 2 * CCH * sizeof(float), stream);
  dw_stats<<<dim3(CCH, BATCH), 256, 0, stream>>>(x, dww, s1, s2);

  for (int b0 = 0; b0 < BATCH; b0 += BC) {
    const float* xc = x + (size_t)b0 * CCH * NPIX;
    float* outc = out + (size_t)b0 * CCH * NPIX;
    transpose_f2b<<<dim3(NPIX / 32, CCH / 32, BC), dim3(32, 8), 0, stream>>>(
        xc, xT, CCH, NPIX);
    gemm_bt<false><<<dim3(NPIX / 128, QKV_M / 128, BC), 256, 0, stream>>>(
        wcat, xT, qkv, nullptr, QKV_M, NPIX, CCH);
    l2norm_qk<<<BC * 256, 256, 0, stream>>>(qkv, BC);
    gate_apply<<<dim3(CCH, BC), 256, 0, stream>>>(xc, dww, s1, s2, gamma, beta, qkv);
    attn_k<<<BC * HEADS, 256, 0, stream>>>(qkv, temp, xT);   // aoT overwrites xT
    gemm_bt<true><<<dim3(NPIX / 128, CCH / 128, BC), 256, 0, stream>>>(
        wpb, xT, outc, bp, CCH, NPIX, CCH);
  }
}

// Round 6
// 336.235 us; speedup vs baseline: 2.2293x; 1.0437x over previous
//
#include <hip/hip_runtime.h>
#include <stdint.h>

#define BATCH 32
#define CCH   512
#define NPIX  1024
#define HEADS 8
#define QKV_M 1536   // q rows 0-511, k rows 512-1023, v rows 1024-1535

typedef short bf16x8 __attribute__((ext_vector_type(8)));
typedef float f32x4 __attribute__((ext_vector_type(4)));

__device__ inline float bf2f(unsigned short u) {
  union { float f; uint32_t i; } t; t.i = ((uint32_t)u) << 16; return t.f;
}
__device__ inline unsigned short f2bf(float f) {
  union { float f; uint32_t u; } t; t.f = f;
  uint32_t u = t.u;
  return (unsigned short)((u + 0x7FFFu + ((u >> 16) & 1u)) >> 16);
}

// async global->LDS, 16B per lane; LDS dest = wave-uniform base + lane*16
__device__ inline void gl_lds16(const unsigned short* g, unsigned short* l) {
  __builtin_amdgcn_global_load_lds(
      (const __attribute__((address_space(1))) uint32_t*)g,
      (__attribute__((address_space(3))) uint32_t*)l, 16, 0, 0);
}

// ---------------- weights fp32 -> bf16 (Wq|Wk|Wv concat, Wp separate) --------
__global__ void convert_w(const float* __restrict__ Wq, const float* __restrict__ Wk,
                          const float* __restrict__ Wv, const float* __restrict__ Wp,
                          unsigned short* __restrict__ wcat,
                          unsigned short* __restrict__ wpb) {
  int i = (blockIdx.x * 256 + threadIdx.x) * 4;   // over CCH*CCH = 262144
  union { ushort4 u4; unsigned short s[4]; } o;
  f32x4 a;
  a = *(const f32x4*)&Wq[i];
  for (int j = 0; j < 4; j++) o.s[j] = f2bf(a[j]);
  *(ushort4*)&wcat[i] = o.u4;
  a = *(const f32x4*)&Wk[i];
  for (int j = 0; j < 4; j++) o.s[j] = f2bf(a[j]);
  *(ushort4*)&wcat[CCH * CCH + i] = o.u4;
  a = *(const f32x4*)&Wv[i];
  for (int j = 0; j < 4; j++) o.s[j] = f2bf(a[j]);
  *(ushort4*)&wcat[2 * CCH * CCH + i] = o.u4;
  a = *(const f32x4*)&Wp[i];
  for (int j = 0; j < 4; j++) o.s[j] = f2bf(a[j]);
  *(ushort4*)&wpb[i] = o.u4;
}

// ---------------- transpose fp32 [b,R,Cc] -> bf16 [b,Cc,R] -------------------
__global__ void transpose_f2b(const float* __restrict__ in,
                              unsigned short* __restrict__ out, int R, int Cc) {
  __shared__ float tile[32][33];
  int b = blockIdx.z;
  int c0 = blockIdx.x * 32;
  int r0 = blockIdx.y * 32;
  const float* inb = in + (size_t)b * R * Cc;
  unsigned short* outb = out + (size_t)b * R * Cc;
  int tx = threadIdx.x, ty = threadIdx.y;
  for (int i = 0; i < 4; i++) {
    int r = ty + i * 8;
    tile[r][tx] = inb[(size_t)(r0 + r) * Cc + c0 + tx];
  }
  __syncthreads();
  for (int i = 0; i < 4; i++) {
    int r = ty + i * 8;
    outb[(size_t)(c0 + r) * R + r0 + tx] = f2bf(tile[tx][r]);
  }
}

// ---------------- gemm_bt: C[b][m][n] = sum_k A[m][k]*X[b][n][k] -------------
// BK=64, XOR-swizzled global_load_lds staging (conflict-free ds_read_b128).
// 128x128 tile, 2x2 waves, mfma 16x16x32, 32 MFMA per barrier-pair.
template <bool OUT_F32>
__launch_bounds__(256)
__global__ void gemm_bt(const unsigned short* __restrict__ A,
                        const unsigned short* __restrict__ X,
                        void* __restrict__ Cout,
                        const float* __restrict__ bias,
                        int M, int N, int K) {
  __shared__ __align__(16) unsigned short As[128 * 64];
  __shared__ __align__(16) unsigned short Bs[128 * 64];
  int b  = blockIdx.z;
  int m0 = blockIdx.y * 128;
  int n0 = blockIdx.x * 128;
  const unsigned short* Xb = X + (size_t)b * N * K;
  int tid = threadIdx.x;
  int lane = tid & 63;
  int wave = tid >> 6;
  int wm = wave >> 1, wn = wave & 1;
  int quad = lane >> 4, l16 = lane & 15;

  f32x4 acc[4][4];
  f32x4 zero = {0.f, 0.f, 0.f, 0.f};
  for (int i = 0; i < 4; i++)
    for (int j = 0; j < 4; j++) acc[i][j] = zero;

  // staging: wave w covers rows [w*32, w*32+32), 4 loads of 8 rows per matrix.
  // lane -> row += lane>>3; fetched k-chunk = (lane&7)^(lane>>3) (XOR swizzle;
  // still one 128B segment per 8-lane row-group -> fully coalesced).
  int r8 = lane >> 3;
  int sw = ((lane & 7) ^ r8) * 8;
  const unsigned short* Ag = A  + (size_t)(m0 + wave * 32 + r8) * K + sw;
  const unsigned short* Xg = Xb + (size_t)(n0 + wave * 32 + r8) * K + sw;
  unsigned short* Al = &As[wave * 32 * 64];
  unsigned short* Bl = &Bs[wave * 32 * 64];

  for (int k0 = 0; k0 < K; k0 += 64) {
    for (int i = 0; i < 4; i++) {
      gl_lds16(Ag + k0 + i * 8 * K, Al + i * 8 * 64);
      gl_lds16(Xg + k0 + i * 8 * K, Bl + i * 8 * 64);
    }
    __syncthreads();
    // fragment read: logical chunk (ks*4+quad) lives at physical ^(l16&7)
    bf16x8 af[2][4], bfr[2][4];
    for (int ks = 0; ks < 2; ks++)
      for (int i = 0; i < 4; i++) {
        int ch = ((ks * 4 + quad) ^ (l16 & 7)) * 8;
        af[ks][i]  = *(const bf16x8*)&As[(wm * 64 + i * 16 + l16) * 64 + ch];
        bfr[ks][i] = *(const bf16x8*)&Bs[(wn * 64 + i * 16 + l16) * 64 + ch];
      }
    for (int ks = 0; ks < 2; ks++)
      for (int i = 0; i < 4; i++)
        for (int j = 0; j < 4; j++)
          acc[i][j] = __builtin_amdgcn_mfma_f32_16x16x32_bf16(
              af[ks][i], bfr[ks][j], acc[i][j], 0, 0, 0);
    __syncthreads();
  }

  // C/D layout: row = quad*4+reg, col = l16
  for (int i = 0; i < 4; i++) {
    int gmb = m0 + wm * 64 + i * 16 + quad * 4;
    for (int j = 0; j < 4; j++) {
      int gn = n0 + wn * 64 + j * 16 + l16;
      for (int r = 0; r < 4; r++) {
        int gm = gmb + r;
        float v = acc[i][j][r];
        if (OUT_F32) {
          v += bias[gm];
          ((float*)Cout)[(size_t)b * M * N + (size_t)gm * N + gn] = v;
        } else {
          ((unsigned short*)Cout)[(size_t)b * M * N + (size_t)gm * N + gn] = f2bf(v);
        }
      }
    }
  }
}

// ---------------- depthwise 3x3 per-channel stats (sum, sumsq) ---------------
__global__ void dw_stats(const float* __restrict__ x,
                         const float* __restrict__ wgt,
                         float* __restrict__ s1, float* __restrict__ s2) {
  int c = blockIdx.x, b = blockIdx.y;
  __shared__ __align__(16) float plane[NPIX];
  const float* xp = x + ((size_t)b * CCH + c) * NPIX;
  *(f32x4*)&plane[threadIdx.x * 4] = *(const f32x4*)&xp[threadIdx.x * 4];
  __syncthreads();
  float w[9];
  for (int i = 0; i < 9; i++) w[i] = wgt[c * 9 + i];
  float a1 = 0.f, a2 = 0.f;
  for (int pi = 0; pi < 4; pi++) {
    int p = threadIdx.x + pi * 256;
    int h = p >> 5, wc = p & 31;
    float v = 0.f;
    for (int dh = -1; dh <= 1; dh++)
      for (int dw = -1; dw <= 1; dw++) {
        int hh = h + dh, ww = wc + dw;
        if (hh >= 0 && hh < 32 && ww >= 0 && ww < 32)
          v += w[(dh + 1) * 3 + dw + 1] * plane[hh * 32 + ww];
      }
    a1 += v; a2 += v * v;
  }
  for (int off = 32; off > 0; off >>= 1) {
    a1 += __shfl_down(a1, off);
    a2 += __shfl_down(a2, off);
  }
  __shared__ float r1[4], r2[4];
  int wv = threadIdx.x >> 6;
  if ((threadIdx.x & 63) == 0) { r1[wv] = a1; r2[wv] = a2; }
  __syncthreads();
  if (threadIdx.x == 0) {
    atomicAdd(&s1[c], r1[0] + r1[1] + r1[2] + r1[3]);
    atomicAdd(&s2[c], r2[0] + r2[1] + r2[2] + r2[3]);
  }
}

// ---------------- gate: v (rows 1024..1535 of qkv) *= SiLU(BN(conv(x))) ------
__global__ void gate_apply(const float* __restrict__ x,
                           const float* __restrict__ wgt,
                           const float* __restrict__ s1, const float* __restrict__ s2,
                           const float* __restrict__ gamma,
                           const float* __restrict__ beta,
                           unsigned short* __restrict__ qkv) {
  int c = blockIdx.x, b = blockIdx.y;
  __shared__ __align__(16) float plane[NPIX];
  const float* xp = x + ((size_t)b * CCH + c) * NPIX;
  unsigned short* vp = qkv + ((size_t)b * QKV_M + 2 * CCH + c) * NPIX;
  *(f32x4*)&plane[threadIdx.x * 4] = *(const f32x4*)&xp[threadIdx.x * 4];
  __syncthreads();
  float w[9];
  for (int i = 0; i < 9; i++) w[i] = wgt[c * 9 + i];
  const float invn = 1.f / 32768.f;
  float mean = s1[c] * invn;
  float var = fmaxf(s2[c] * invn - mean * mean, 0.f);
  float rstd = rsqrtf(var + 1e-5f);
  float ga = gamma[c], be = beta[c];
  for (int pi = 0; pi < 4; pi++) {
    int p = threadIdx.x + pi * 256;
    int h = p >> 5, wc = p & 31;
    float val = 0.f;
    for (int dh = -1; dh <= 1; dh++)
      for (int dw = -1; dw <= 1; dw++) {
        int hh = h + dh, ww = wc + dw;
        if (hh >= 0 && hh < 32 && ww >= 0 && ww < 32)
          val += w[(dh + 1) * 3 + dw + 1] * plane[hh * 32 + ww];
      }
    float g = (val - mean) * rstd * ga + be;
    float sg = g / (1.f + __expf(-g));      // SiLU
    vp[p] = f2bf(bf2f(vp[p]) * sg);
  }
}

// ---------------- attn_s: S=QK^T (+ fused l2norm via QQ^T/KK^T diag),
//                  softmax -> P [bh][64][64] bf16 -------------------------------
__launch_bounds__(256)
__global__ void attn_s(const unsigned short* __restrict__ qkv,
                       const float* __restrict__ temp,
                       unsigned short* __restrict__ P) {
  int bh = blockIdx.x;
  int b = bh >> 3, h = bh & 7;
  const unsigned short* Q = qkv + ((size_t)b * QKV_M + h * 64) * NPIX;
  const unsigned short* K = Q + (size_t)CCH * NPIX;
  int tid = threadIdx.x, lane = tid & 63, wave = tid >> 6;
  int quad = lane >> 4, l16 = lane & 15;

  __shared__ __align__(16) float Sf[64][65];
  __shared__ float qq[64], kk[64], invq[64], invk[64];
  __shared__ float redm[4][64], reds[4][64];

  f32x4 zero = {0.f, 0.f, 0.f, 0.f};
  f32x4 acc[4], accQ = zero, accK = zero;
  for (int j = 0; j < 4; j++) acc[j] = zero;
  for (int n0 = 0; n0 < NPIX; n0 += 32) {
    bf16x8 a  = *(const bf16x8*)&Q[(size_t)(wave * 16 + l16) * NPIX + n0 + quad * 8];
    bf16x8 ak = *(const bf16x8*)&K[(size_t)(wave * 16 + l16) * NPIX + n0 + quad * 8];
    accQ = __builtin_amdgcn_mfma_f32_16x16x32_bf16(a, a, accQ, 0, 0, 0);
    accK = __builtin_amdgcn_mfma_f32_16x16x32_bf16(ak, ak, accK, 0, 0, 0);
    for (int j = 0; j < 4; j++) {
      bf16x8 bb = *(const bf16x8*)&K[(size_t)(j * 16 + l16) * NPIX + n0 + quad * 8];
      acc[j] = __builtin_amdgcn_mfma_f32_16x16x32_bf16(a, bb, acc[j], 0, 0, 0);
    }
  }
  for (int j = 0; j < 4; j++)
    for (int r = 0; r < 4; r++)
      Sf[wave * 16 + quad * 4 + r][j * 16 + l16] = acc[j][r];
  // diagonal of Q.Q^T / K.K^T: D row=quad*4+r, col=l16 -> diag where equal
  for (int r = 0; r < 4; r++)
    if (l16 == quad * 4 + r) {
      qq[wave * 16 + l16] = accQ[r];
      kk[wave * 16 + l16] = accK[r];
    }
  __syncthreads();
  if (tid < 64) invq[tid] = 1.f / fmaxf(sqrtf(qq[tid]), 1e-12f);
  else if (tid < 128) invk[tid - 64] = 1.f / fmaxf(sqrtf(kk[tid - 64]), 1e-12f);
  __syncthreads();

  // softmax over e: 256 threads = 64 rows x 4 segments of 16
  int row = tid & 63, seg = tid >> 6;
  float fq = temp[h] * invq[row];
  float v[16], pm = -1e30f;
  for (int i = 0; i < 16; i++) {
    v[i] = Sf[row][seg * 16 + i] * fq * invk[seg * 16 + i];
    pm = fmaxf(pm, v[i]);
  }
  redm[seg][row] = pm;
  __syncthreads();
  float m = fmaxf(fmaxf(redm[0][row], redm[1][row]),
                  fmaxf(redm[2][row], redm[3][row]));
  float ps = 0.f;
  for (int i = 0; i < 16; i++) { v[i] = __expf(v[i] - m); ps += v[i]; }
  reds[seg][row] = ps;
  __syncthreads();
  float inv = 1.f / (reds[0][row] + reds[1][row] + reds[2][row] + reds[3][row]);
  union { uint4 q4[2]; unsigned short s[16]; } u;
  for (int i = 0; i < 16; i++) u.s[i] = f2bf(v[i] * inv);
  unsigned short* Pp = P + ((size_t)bh * 64 + row) * 64 + seg * 16;
  *(uint4*)&Pp[0] = u.q4[0];
  *(uint4*)&Pp[8] = u.q4[1];
}

// ---------------- attn_o: O^T[n][d] = sum_e V^T[n][e] P[d][e] ----------------
// grid = bh*4 (n-quarters); register-prefetched V, LDS-staged coalesced stores.
__launch_bounds__(256)
__global__ void attn_o(const unsigned short* __restrict__ qkv,
                       const unsigned short* __restrict__ P,
                       unsigned short* __restrict__ aoT) {
  int blk = blockIdx.x;
  int nc = blk & 3, bh = blk >> 2;
  int b = bh >> 3, h = bh & 7;
  const unsigned short* V = qkv + ((size_t)b * QKV_M + 2 * CCH + h * 64) * NPIX;
  unsigned short* Ob = aoT + (size_t)b * NPIX * CCH + h * 64;
  int tid = threadIdx.x, lane = tid & 63, wave = tid >> 6;
  int quad = lane >> 4, l16 = lane & 15;

  __shared__ __align__(16) unsigned short Vt[4][16][72];
  __shared__ __align__(16) unsigned short Ot[4][16][72];

  // P fragments (B-operand: row d = j*16+l16, k = e)
  const unsigned short* Pb = P + (size_t)bh * 64 * 64;
  bf16x8 Pf[4][2];
  for (int j = 0; j < 4; j++)
    for (int ks = 0; ks < 2; ks++)
      Pf[j][ks] = *(const bf16x8*)&Pb[(j * 16 + l16) * 64 + ks * 32 + quad * 8];

  f32x4 zero = {0.f, 0.f, 0.f, 0.f};
  int e1 = lane >> 1, noff = (lane & 1) * 8;
  int nbase = nc * 256 + wave * 64;
  int orow = lane >> 3, ocol = (lane & 7) * 8;

  union { uint4 q; unsigned short s[8]; } g0, g1, c0, c1;
  g0.q = *(const uint4*)&V[(size_t)e1 * NPIX + nbase + noff];
  g1.q = *(const uint4*)&V[(size_t)(e1 + 32) * NPIX + nbase + noff];
#pragma unroll
  for (int nt = 0; nt < 4; nt++) {
    int n0 = nbase + nt * 16;
    c0 = g0; c1 = g1;
    if (nt < 3) {
      g0.q = *(const uint4*)&V[(size_t)e1 * NPIX + n0 + 16 + noff];
      g1.q = *(const uint4*)&V[(size_t)(e1 + 32) * NPIX + n0 + 16 + noff];
    }
    for (int jj = 0; jj < 8; jj++) {
      Vt[wave][noff + jj][e1]      = c0.s[jj];
      Vt[wave][noff + jj][e1 + 32] = c1.s[jj];
    }
    bf16x8 Af0 = *(const bf16x8*)&Vt[wave][l16][quad * 8];
    bf16x8 Af1 = *(const bf16x8*)&Vt[wave][l16][32 + quad * 8];
    f32x4 oacc[4];
    for (int j = 0; j < 4; j++) {
      oacc[j] = __builtin_amdgcn_mfma_f32_16x16x32_bf16(Af0, Pf[j][0], zero, 0, 0, 0);
      oacc[j] = __builtin_amdgcn_mfma_f32_16x16x32_bf16(Af1, Pf[j][1], oacc[j], 0, 0, 0);
    }
    for (int j = 0; j < 4; j++)
      for (int r = 0; r < 4; r++)
        Ot[wave][quad * 4 + r][j * 16 + l16] = f2bf(oacc[j][r]);
    uint4 o0 = *(const uint4*)&Ot[wave][orow][ocol];
    uint4 o1 = *(const uint4*)&Ot[wave][orow + 8][ocol];
    *(uint4*)&Ob[(size_t)(n0 + orow) * CCH + ocol] = o0;
    *(uint4*)&Ob[(size_t)(n0 + orow + 8) * CCH + ocol] = o1;
  }
}

// ---------------------------------------------------------------------------
extern "C" void kernel_launch(void* const* d_in, const int* in_sizes, int n_in,
                              void* d_out, int out_size, void* d_ws, size_t ws_size,
                              hipStream_t stream) {
  const float* x     = (const float*)d_in[0];
  const float* Wq    = (const float*)d_in[1];
  const float* Wk    = (const float*)d_in[2];
  const float* Wv    = (const float*)d_in[3];
  const float* dww   = (const float*)d_in[4];
  const float* gamma = (const float*)d_in[5];
  const float* beta  = (const float*)d_in[6];
  const float* temp  = (const float*)d_in[7];
  const float* Wp    = (const float*)d_in[8];
  const float* bp    = (const float*)d_in[9];
  float* out = (float*)d_out;

  char* ws = (char*)d_ws;
  unsigned short* wcat = (unsigned short*)ws;             // [1536,512] bf16
  unsigned short* wpb  = wcat + (size_t)QKV_M * CCH;      // [512,512] bf16
  float* s1 = (float*)(wpb + (size_t)CCH * CCH);
  float* s2 = s1 + CCH;
  unsigned short* Pbuf = (unsigned short*)(s2 + CCH);     // [B*H,64,64] bf16, 2MB
  char* dyn = (char*)(Pbuf + (size_t)BATCH * HEADS * 64 * 64);
  size_t fixed = (size_t)(dyn - ws);
  size_t per_b = ((size_t)NPIX * CCH + (size_t)QKV_M * NPIX) * 2;  // 4 MB/batch
  int BC = BATCH;
  while (BC > 1 && fixed + (size_t)BC * per_b > ws_size) BC >>= 1;
  unsigned short* xT  = (unsigned short*)dyn;                  // [BC,N,C]; reused as aoT
  unsigned short* qkv = xT + (size_t)BC * NPIX * CCH;          // [BC,1536,N]

  convert_w<<<CCH * CCH / 1024, 256, 0, stream>>>(Wq, Wk, Wv, Wp, wcat, wpb);
  hipMemsetAsync(s1, 0, 2 * CCH * sizeof(float), stream);
  dw_stats<<<dim3(CCH, BATCH), 256, 0, stream>>>(x, dww, s1, s2);

  for (int b0 = 0; b0 < BATCH; b0 += BC) {
    const float* xc = x + (size_t)b0 * CCH * NPIX;
    float* outc = out + (size_t)b0 * CCH * NPIX;
    transpose_f2b<<<dim3(NPIX / 32, CCH / 32, BC), dim3(32, 8), 0, stream>>>(
        xc, xT, CCH, NPIX);
    gemm_bt<false><<<dim3(NPIX / 128, QKV_M / 128, BC), 256, 0, stream>>>(
        wcat, xT, qkv, nullptr, QKV_M, NPIX, CCH);
    attn_s<<<BC * HEADS, 256, 0, stream>>>(qkv, temp, Pbuf);
    gate_apply<<<dim3(CCH, BC), 256, 0, stream>>>(xc, dww, s1, s2, gamma, beta, qkv);
    attn_o<<<BC * HEADS * 4, 256, 0, stream>>>(qkv, Pbuf, xT);  // aoT overwrites xT
    gemm_bt<true><<<dim3(NPIX / 128, CCH / 128, BC), 256, 0, stream>>>(
        wpb, xT, outc, bp, CCH, NPIX, CCH);
  }
}